// Round 4
// baseline (447.975 us; speedup 1.0000x reference)
//
#include <hip/hip_runtime.h>
#include <math.h>

// Problem constants
#define BATCH 256
#define IC    1152
#define EDIM  8
#define NC    10
#define DV    16

// Tiling
#define ITILE  8                    // i's covered by thread layout (il = 0..7)
#define NCHUNK 4                    // i-chunks looped per block
#define ITOT   (ITILE * NCHUNK)     // 32 i's per block
#define NB     8                    // b's per block (looped, register s-acc)
#define NTHREADS 256                // 8 il * 2 ch * 16 d
#define NWAVES 4
#define NSLAB  (IC / ITOT)          // 36 partial slabs
#define BCHUNKS (BATCH / NB)        // 32
#define SCD (NC * DV)               // 160
#define SPART_STRIDE (BATCH * SCD)  // 40960 floats per slab

// ---------------------------------------------------------------------------
// DPP-based 16-lane (row) sum reduce — all VALU, no DS pipe. HW-verified.
// ---------------------------------------------------------------------------
template<int CTRL>
__device__ __forceinline__ float dpp_add(float x) {
    int r = __builtin_amdgcn_update_dpp(0, __float_as_int(x), CTRL, 0xF, 0xF, true);
    return x + __int_as_float(r);
}
__device__ __forceinline__ float row_reduce16(float x) {
    x = dpp_add<0xB1>(x);   // quad_perm [1,0,3,2] : xor 1
    x = dpp_add<0x4E>(x);   // quad_perm [2,3,0,1] : xor 2
    x = dpp_add<0x141>(x);  // row_half_mirror     : xor 4
    x = dpp_add<0x140>(x);  // row_mirror          : xor 8
    return x;
}

// ---------------------------------------------------------------------------
// Main fused kernel. tid = il*32 + ch*16 + d.
// Loop: ic (4 i-chunks, W reloaded per chunk) outer, bb (8 b's) inner.
// s-partials accumulate in REGISTERS sacc[8][5] across the whole nest;
// one shuffle+LDS+barrier reduction in the epilogue only.
// MODE 1: c = softmax(bias)                       -> s1 partials
// MODE 2: b2 = (u.v1) + 2*bias (stored), softmax  -> s2 partials
// MODE 3: b3 = (u.v2) + b2 + bias, softmax        -> s3 partials
// ---------------------------------------------------------------------------
template<int MODE>
__global__ __launch_bounds__(NTHREADS, 4)
void caps_main(const float* __restrict__ x,
               const float* __restrict__ W,
               const float* __restrict__ bias,
               const float* __restrict__ v_in,
               float* __restrict__ b2,
               float* __restrict__ s_part)
{
    __shared__ float sx[NB][ITOT * EDIM];    // 8 KB
    __shared__ float swv[NWAVES][NB][SCD];   // 20 KB — wave-private slabs

    const int tid = threadIdx.x;
    const int d   = tid & 15;
    const int ch  = (tid >> 4) & 1;
    const int il  = tid >> 5;                // 0..7
    const int wid = tid >> 6;                // 0..3
    const int icb = blockIdx.x;              // 0..35
    const int bcb = blockIdx.y;              // 0..31
    const int i0  = icb * ITOT;
    const int b0  = bcb * NB;

    // ---- stage x slice: 512 float4, 2 per thread, coalesced ----
    {
        const float4* xg = (const float4*)x;
        float4* xs = (float4*)&sx[0][0];
        #pragma unroll
        for (int f = tid; f < NB * ITOT * EDIM / 4; f += NTHREADS) {
            int bb = f >> 6;                 // 64 float4 per b row
            int w  = f & 63;
            xs[f] = xg[(size_t)(b0 + bb) * (IC * EDIM / 4) + i0 * (EDIM / 4) + w];
        }
    }

    float sacc[NB][5];
    #pragma unroll
    for (int bb = 0; bb < NB; ++bb)
        #pragma unroll
        for (int k = 0; k < 5; ++k) sacc[bb][k] = 0.f;

    __syncthreads();

    const float4* Wg = (const float4*)W;

    #pragma unroll 1
    for (int ic = 0; ic < NCHUNK; ++ic) {
        const int i = i0 + ic * ITILE + il;

        // W fragment + bias for this i-chunk
        float4 w4[5][2];
        float  bv[5];
        #pragma unroll
        for (int k = 0; k < 5; ++k) {
            int c = ch * 5 + k;
            size_t base = ((size_t)(i * NC + c) * DV + d) * 2;
            w4[k][0] = Wg[base];
            w4[k][1] = Wg[base + 1];
            bv[k]    = bias[i * NC + c];
        }

        float cw[5];
        if (MODE == 1) {
            // softmax(bias[i,:]) — batch-independent, once per i-chunk
            float mx = fmaxf(fmaxf(fmaxf(bv[0], bv[1]), fmaxf(bv[2], bv[3])), bv[4]);
            mx = fmaxf(mx, __shfl_xor(mx, 16));
            float ssum = 0.f, ex[5];
            #pragma unroll
            for (int k = 0; k < 5; ++k) { ex[k] = __expf(bv[k] - mx); ssum += ex[k]; }
            ssum += __shfl_xor(ssum, 16);
            float inv = 1.0f / ssum;
            #pragma unroll
            for (int k = 0; k < 5; ++k) cw[k] = ex[k] * inv;
        }

        #pragma unroll
        for (int bb = 0; bb < NB; ++bb) {
            const int b = b0 + bb;
            const float4 x0 = ((const float4*)&sx[bb][(ic * ITILE + il) * EDIM])[0];
            const float4 x1 = ((const float4*)&sx[bb][(ic * ITILE + il) * EDIM])[1];

            // u_hat[b, i, c_k, d]
            float u[5];
            #pragma unroll
            for (int k = 0; k < 5; ++k) {
                float acc = w4[k][0].x * x0.x;
                acc = fmaf(w4[k][0].y, x0.y, acc);
                acc = fmaf(w4[k][0].z, x0.z, acc);
                acc = fmaf(w4[k][0].w, x0.w, acc);
                acc = fmaf(w4[k][1].x, x1.x, acc);
                acc = fmaf(w4[k][1].y, x1.y, acc);
                acc = fmaf(w4[k][1].z, x1.z, acc);
                acc = fmaf(w4[k][1].w, x1.w, acc);
                u[k] = acc;
            }

            if (MODE != 1) {
                // agreement: sum over d via DPP; v is small & L2-hot
                const float* vb = v_in + (size_t)b * SCD + ch * 80 + d;
                float t[5];
                #pragma unroll
                for (int k = 0; k < 5; ++k) t[k] = u[k] * vb[k * 16];
                #pragma unroll
                for (int k = 0; k < 5; ++k) t[k] = row_reduce16(t[k]);

                float br[5];
                if (MODE == 2) {
                    #pragma unroll
                    for (int k = 0; k < 5; ++k) br[k] = t[k] + 2.0f * bv[k];
                    if (d == 0) {
                        float* bp = b2 + ((size_t)b * IC + i) * NC + ch * 5;
                        #pragma unroll
                        for (int k = 0; k < 5; ++k) bp[k] = br[k];
                    }
                } else {
                    const float* bp = b2 + ((size_t)b * IC + i) * NC + ch * 5;
                    #pragma unroll
                    for (int k = 0; k < 5; ++k) br[k] = t[k] + bp[k] + bv[k];
                }
                // softmax over 10 c's: 5 local + partner half via xor-16
                float mx = fmaxf(fmaxf(fmaxf(br[0], br[1]), fmaxf(br[2], br[3])), br[4]);
                mx = fmaxf(mx, __shfl_xor(mx, 16));
                float ssum = 0.f, ex[5];
                #pragma unroll
                for (int k = 0; k < 5; ++k) { ex[k] = __expf(br[k] - mx); ssum += ex[k]; }
                ssum += __shfl_xor(ssum, 16);
                float inv = 1.0f / ssum;
                #pragma unroll
                for (int k = 0; k < 5; ++k) cw[k] = ex[k] * inv;
            }

            // register s-accumulation — no LDS, no shuffle, no barrier
            #pragma unroll
            for (int k = 0; k < 5; ++k)
                sacc[bb][k] = fmaf(cw[k], u[k], sacc[bb][k]);
        }
    }

    // ---- epilogue: i-pair reduce + wave slabs + 4-way reduce + flush ----
    #pragma unroll
    for (int bb = 0; bb < NB; ++bb) {
        #pragma unroll
        for (int k = 0; k < 5; ++k) {
            float s = sacc[bb][k] + __shfl_xor(sacc[bb][k], 32);
            if ((tid & 32) == 0)
                swv[wid][bb][ch * 80 + k * 16 + d] = s;
        }
    }
    __syncthreads();
    #pragma unroll
    for (int r = 0; r < (NB * SCD) / NTHREADS; ++r) {   // 5 iterations
        int j  = tid + r * NTHREADS;
        int bb = j / SCD;
        int cd = j - bb * SCD;
        float s = (swv[0][bb][cd] + swv[1][bb][cd])
                + (swv[2][bb][cd] + swv[3][bb][cd]);
        s_part[((size_t)icb * BATCH + b0 + bb) * SCD + cd] = s;
    }
}

// ---------------------------------------------------------------------------
// Reduce s-partials over the 36 slabs and apply squash.
// Block = 16 (b,c) groups x 16 d. Grid = 2560/16 = 160 blocks.
// ---------------------------------------------------------------------------
__global__ __launch_bounds__(256)
void caps_squash(const float* __restrict__ s_part, float* __restrict__ out)
{
    const int tid = threadIdx.x;
    const int bc  = blockIdx.x * 16 + (tid >> 4);
    const size_t off = (size_t)bc * DV + (tid & 15);

    float a[4] = {0.f, 0.f, 0.f, 0.f};
    #pragma unroll
    for (int ic = 0; ic < NSLAB; ic += 4) {
        #pragma unroll
        for (int j = 0; j < 4; ++j)
            a[j] += s_part[(size_t)(ic + j) * SPART_STRIDE + off];
    }
    float s = (a[0] + a[1]) + (a[2] + a[3]);

    float sq = row_reduce16(s * s);

    // scale = sq/(1+sq)/sqrt(sq+EPS), EPS = 1e-7 (matches reference)
    float scale = sq / ((1.0f + sq) * sqrtf(sq + 1e-7f));
    out[off] = scale * s;
}

// ---------------------------------------------------------------------------
extern "C" void kernel_launch(void* const* d_in, const int* in_sizes, int n_in,
                              void* d_out, int out_size, void* d_ws, size_t ws_size,
                              hipStream_t stream)
{
    const float* x    = (const float*)d_in[0];   // [256,1152,8]
    const float* W    = (const float*)d_in[1];   // [1152,10,16,8]
    const float* bias = (const float*)d_in[2];   // [1152,10]
    float* out = (float*)d_out;                  // [256,10,16]

    float* ws     = (float*)d_ws;
    float* s_part = ws;                                       // 36*40960 = 1,474,560 f
    float* v      = s_part + (size_t)NSLAB * SPART_STRIDE;    // 40,960 f
    float* b2     = v + SPART_STRIDE;                         // 2,949,120 f
    // total ws use: ~17.9 MB

    dim3 grid(NSLAB, BCHUNKS);   // 36 x 32 = 1152 blocks

    // iter 1
    caps_main<1><<<grid, NTHREADS, 0, stream>>>(x, W, bias, v, b2, s_part);
    caps_squash<<<160, 256, 0, stream>>>(s_part, v);
    // iter 2
    caps_main<2><<<grid, NTHREADS, 0, stream>>>(x, W, bias, v, b2, s_part);
    caps_squash<<<160, 256, 0, stream>>>(s_part, v);
    // final
    caps_main<3><<<grid, NTHREADS, 0, stream>>>(x, W, bias, v, b2, s_part);
    caps_squash<<<160, 256, 0, stream>>>(s_part, out);
}

// Round 5
// 300.602 us; speedup vs baseline: 1.4903x; 1.4903x over previous
//
#include <hip/hip_runtime.h>
#include <math.h>

// Problem constants
#define BATCH 256
#define IC    1152
#define EDIM  8
#define NC    10
#define DV    16

// Tiling
#define ITILE  8                    // i's covered by thread layout (il = 0..7)
#define NCHUNK 4                    // i-chunks looped per block
#define ITOT   (ITILE * NCHUNK)     // 32 i's per block
#define NB     8                    // b's per block (looped, register s-acc)
#define NTHREADS 256                // 8 il * 2 ch * 16 d
#define NWAVES 4
#define NSLAB  (IC / ITOT)          // 36 partial slabs
#define BCHUNKS (BATCH / NB)        // 32
#define SCD (NC * DV)               // 160
#define SPART_STRIDE (BATCH * SCD)  // 40960 floats per slab

// ---------------------------------------------------------------------------
// DPP-based 16-lane (row) sum reduce — all VALU, no DS pipe. HW-verified.
// ---------------------------------------------------------------------------
template<int CTRL>
__device__ __forceinline__ float dpp_add(float x) {
    int r = __builtin_amdgcn_update_dpp(0, __float_as_int(x), CTRL, 0xF, 0xF, true);
    return x + __int_as_float(r);
}
__device__ __forceinline__ float row_reduce16(float x) {
    x = dpp_add<0xB1>(x);   // quad_perm [1,0,3,2] : xor 1
    x = dpp_add<0x4E>(x);   // quad_perm [2,3,0,1] : xor 2
    x = dpp_add<0x141>(x);  // row_half_mirror     : xor 4
    x = dpp_add<0x140>(x);  // row_mirror          : xor 8
    return x;
}

// ---------------------------------------------------------------------------
// Main fused kernel. tid = il*32 + ch*16 + d.
// Loop: ic (4 i-chunks, W reloaded per chunk) outer, bb (8 b's) inner.
// s-partials accumulate in REGISTERS sacc[8][5]; one shuffle+LDS reduction
// in the epilogue only.
// NOTE: __launch_bounds__(256,3) — cap 170 VGPRs. Round 4 used (256,4)
// (cap 128) and the compiler spilled sacc to scratch: VGPR_Count fell to 64
// and FETCH+WRITE ballooned to ~580 MB/dispatch (all scratch traffic).
// Kernel needs ~130 VGPRs; do NOT tighten this bound.
// MODE 1: c = softmax(bias)                       -> s1 partials
// MODE 2: b2 = (u.v1) + 2*bias (stored), softmax  -> s2 partials
// MODE 3: b3 = (u.v2) + b2 + bias, softmax        -> s3 partials
// ---------------------------------------------------------------------------
template<int MODE>
__global__ __launch_bounds__(NTHREADS, 3)
void caps_main(const float* __restrict__ x,
               const float* __restrict__ W,
               const float* __restrict__ bias,
               const float* __restrict__ v_in,
               float* __restrict__ b2,
               float* __restrict__ s_part)
{
    __shared__ float sx[NB][ITOT * EDIM];    // 8 KB
    __shared__ float swv[NWAVES][NB][SCD];   // 20 KB — wave-private slabs

    const int tid = threadIdx.x;
    const int d   = tid & 15;
    const int ch  = (tid >> 4) & 1;
    const int il  = tid >> 5;                // 0..7
    const int wid = tid >> 6;                // 0..3
    const int icb = blockIdx.x;              // 0..35
    const int bcb = blockIdx.y;              // 0..31
    const int i0  = icb * ITOT;
    const int b0  = bcb * NB;

    // ---- stage x slice: 512 float4, 2 per thread, coalesced ----
    {
        const float4* xg = (const float4*)x;
        float4* xs = (float4*)&sx[0][0];
        #pragma unroll
        for (int f = tid; f < NB * ITOT * EDIM / 4; f += NTHREADS) {
            int bb = f >> 6;                 // 64 float4 per b row
            int w  = f & 63;
            xs[f] = xg[(size_t)(b0 + bb) * (IC * EDIM / 4) + i0 * (EDIM / 4) + w];
        }
    }

    float sacc[NB][5];
    #pragma unroll
    for (int bb = 0; bb < NB; ++bb)
        #pragma unroll
        for (int k = 0; k < 5; ++k) sacc[bb][k] = 0.f;

    __syncthreads();

    const float4* Wg = (const float4*)W;

    #pragma unroll 1
    for (int ic = 0; ic < NCHUNK; ++ic) {
        const int i = i0 + ic * ITILE + il;

        // W fragment + bias for this i-chunk
        float4 w4[5][2];
        float  bv[5];
        #pragma unroll
        for (int k = 0; k < 5; ++k) {
            int c = ch * 5 + k;
            size_t base = ((size_t)(i * NC + c) * DV + d) * 2;
            w4[k][0] = Wg[base];
            w4[k][1] = Wg[base + 1];
            bv[k]    = bias[i * NC + c];
        }

        float cw[5];
        if (MODE == 1) {
            // softmax(bias[i,:]) — batch-independent, once per i-chunk
            float mx = fmaxf(fmaxf(fmaxf(bv[0], bv[1]), fmaxf(bv[2], bv[3])), bv[4]);
            mx = fmaxf(mx, __shfl_xor(mx, 16));
            float ssum = 0.f, ex[5];
            #pragma unroll
            for (int k = 0; k < 5; ++k) { ex[k] = __expf(bv[k] - mx); ssum += ex[k]; }
            ssum += __shfl_xor(ssum, 16);
            float inv = 1.0f / ssum;
            #pragma unroll
            for (int k = 0; k < 5; ++k) cw[k] = ex[k] * inv;
        }

        #pragma unroll
        for (int bb = 0; bb < NB; ++bb) {
            const int b = b0 + bb;
            const float4 x0 = ((const float4*)&sx[bb][(ic * ITILE + il) * EDIM])[0];
            const float4 x1 = ((const float4*)&sx[bb][(ic * ITILE + il) * EDIM])[1];

            // u_hat[b, i, c_k, d]
            float u[5];
            #pragma unroll
            for (int k = 0; k < 5; ++k) {
                float acc = w4[k][0].x * x0.x;
                acc = fmaf(w4[k][0].y, x0.y, acc);
                acc = fmaf(w4[k][0].z, x0.z, acc);
                acc = fmaf(w4[k][0].w, x0.w, acc);
                acc = fmaf(w4[k][1].x, x1.x, acc);
                acc = fmaf(w4[k][1].y, x1.y, acc);
                acc = fmaf(w4[k][1].z, x1.z, acc);
                acc = fmaf(w4[k][1].w, x1.w, acc);
                u[k] = acc;
            }

            if (MODE != 1) {
                // agreement: sum over d via DPP; v is small & L2-hot
                const float* vb = v_in + (size_t)b * SCD + ch * 80 + d;
                float t[5];
                #pragma unroll
                for (int k = 0; k < 5; ++k) t[k] = u[k] * vb[k * 16];
                #pragma unroll
                for (int k = 0; k < 5; ++k) t[k] = row_reduce16(t[k]);

                float br[5];
                if (MODE == 2) {
                    #pragma unroll
                    for (int k = 0; k < 5; ++k) br[k] = t[k] + 2.0f * bv[k];
                    if (d == 0) {
                        float* bp = b2 + ((size_t)b * IC + i) * NC + ch * 5;
                        #pragma unroll
                        for (int k = 0; k < 5; ++k) bp[k] = br[k];
                    }
                } else {
                    const float* bp = b2 + ((size_t)b * IC + i) * NC + ch * 5;
                    #pragma unroll
                    for (int k = 0; k < 5; ++k) br[k] = t[k] + bp[k] + bv[k];
                }
                // softmax over 10 c's: 5 local + partner half via xor-16
                float mx = fmaxf(fmaxf(fmaxf(br[0], br[1]), fmaxf(br[2], br[3])), br[4]);
                mx = fmaxf(mx, __shfl_xor(mx, 16));
                float ssum = 0.f, ex[5];
                #pragma unroll
                for (int k = 0; k < 5; ++k) { ex[k] = __expf(br[k] - mx); ssum += ex[k]; }
                ssum += __shfl_xor(ssum, 16);
                float inv = 1.0f / ssum;
                #pragma unroll
                for (int k = 0; k < 5; ++k) cw[k] = ex[k] * inv;
            }

            // register s-accumulation — no LDS, no shuffle, no barrier
            #pragma unroll
            for (int k = 0; k < 5; ++k)
                sacc[bb][k] = fmaf(cw[k], u[k], sacc[bb][k]);
        }
    }

    // ---- epilogue: i-pair reduce + wave slabs + 4-way reduce + flush ----
    #pragma unroll
    for (int bb = 0; bb < NB; ++bb) {
        #pragma unroll
        for (int k = 0; k < 5; ++k) {
            float s = sacc[bb][k] + __shfl_xor(sacc[bb][k], 32);
            if ((tid & 32) == 0)
                swv[wid][bb][ch * 80 + k * 16 + d] = s;
        }
    }
    __syncthreads();
    #pragma unroll
    for (int r = 0; r < (NB * SCD) / NTHREADS; ++r) {   // 5 iterations
        int j  = tid + r * NTHREADS;
        int bb = j / SCD;
        int cd = j - bb * SCD;
        float s = (swv[0][bb][cd] + swv[1][bb][cd])
                + (swv[2][bb][cd] + swv[3][bb][cd]);
        s_part[((size_t)icb * BATCH + b0 + bb) * SCD + cd] = s;
    }
}

// ---------------------------------------------------------------------------
// Reduce s-partials over the 36 slabs and apply squash.
// Block = 16 (b,c) groups x 16 d. Grid = 2560/16 = 160 blocks.
// ---------------------------------------------------------------------------
__global__ __launch_bounds__(256)
void caps_squash(const float* __restrict__ s_part, float* __restrict__ out)
{
    const int tid = threadIdx.x;
    const int bc  = blockIdx.x * 16 + (tid >> 4);
    const size_t off = (size_t)bc * DV + (tid & 15);

    float a[4] = {0.f, 0.f, 0.f, 0.f};
    #pragma unroll
    for (int ic = 0; ic < NSLAB; ic += 4) {
        #pragma unroll
        for (int j = 0; j < 4; ++j)
            a[j] += s_part[(size_t)(ic + j) * SPART_STRIDE + off];
    }
    float s = (a[0] + a[1]) + (a[2] + a[3]);

    float sq = row_reduce16(s * s);

    // scale = sq/(1+sq)/sqrt(sq+EPS), EPS = 1e-7 (matches reference)
    float scale = sq / ((1.0f + sq) * sqrtf(sq + 1e-7f));
    out[off] = scale * s;
}

// ---------------------------------------------------------------------------
extern "C" void kernel_launch(void* const* d_in, const int* in_sizes, int n_in,
                              void* d_out, int out_size, void* d_ws, size_t ws_size,
                              hipStream_t stream)
{
    const float* x    = (const float*)d_in[0];   // [256,1152,8]
    const float* W    = (const float*)d_in[1];   // [1152,10,16,8]
    const float* bias = (const float*)d_in[2];   // [1152,10]
    float* out = (float*)d_out;                  // [256,10,16]

    float* ws     = (float*)d_ws;
    float* s_part = ws;                                       // 36*40960 = 1,474,560 f
    float* v      = s_part + (size_t)NSLAB * SPART_STRIDE;    // 40,960 f
    float* b2     = v + SPART_STRIDE;                         // 2,949,120 f
    // total ws use: ~17.9 MB

    dim3 grid(NSLAB, BCHUNKS);   // 36 x 32 = 1152 blocks

    // iter 1
    caps_main<1><<<grid, NTHREADS, 0, stream>>>(x, W, bias, v, b2, s_part);
    caps_squash<<<160, 256, 0, stream>>>(s_part, v);
    // iter 2
    caps_main<2><<<grid, NTHREADS, 0, stream>>>(x, W, bias, v, b2, s_part);
    caps_squash<<<160, 256, 0, stream>>>(s_part, v);
    // final
    caps_main<3><<<grid, NTHREADS, 0, stream>>>(x, W, bias, v, b2, s_part);
    caps_squash<<<160, 256, 0, stream>>>(s_part, out);
}

// Round 6
// 197.311 us; speedup vs baseline: 2.2704x; 1.5235x over previous
//
#include <hip/hip_runtime.h>
#include <math.h>

// Problem constants
#define BATCH 256
#define IC    1152
#define EDIM  8
#define NC    10
#define DV    16

// Tiling
#define ITILE  8                    // i's covered by thread layout (il = 0..7)
#define NCHUNK 4                    // i-chunks looped per block
#define ITOT   (ITILE * NCHUNK)     // 32 i's per block
#define NB     8                    // b's per block (looped, register s-acc)
#define NTHREADS 256                // 8 il * 2 ch * 16 d
#define NWAVES 4
#define NSLAB  (IC / ITOT)          // 36 partial slabs
#define BCHUNKS (BATCH / NB)        // 32
#define SCD (NC * DV)               // 160
#define SPART_STRIDE (BATCH * SCD)  // 40960 floats per slab

// ---------------------------------------------------------------------------
// DPP-based 16-lane (row) sum reduce — all VALU, no DS pipe. HW-verified.
// ---------------------------------------------------------------------------
template<int CTRL>
__device__ __forceinline__ float dpp_add(float x) {
    int r = __builtin_amdgcn_update_dpp(0, __float_as_int(x), CTRL, 0xF, 0xF, true);
    return x + __int_as_float(r);
}
__device__ __forceinline__ float row_reduce16(float x) {
    x = dpp_add<0xB1>(x);   // quad_perm [1,0,3,2] : xor 1
    x = dpp_add<0x4E>(x);   // quad_perm [2,3,0,1] : xor 2
    x = dpp_add<0x141>(x);  // row_half_mirror     : xor 4
    x = dpp_add<0x140>(x);  // row_mirror          : xor 8
    return x;
}

// ---------------------------------------------------------------------------
// Main fused kernel. tid = il*32 + ch*16 + d.
// Loop: ic (4 i-chunks, W reloaded per chunk) outer, bb (8 b's) inner.
// s-partials accumulate in REGISTERS sacc[8][5]; one shuffle+LDS reduction
// in the epilogue only.
//
// SPILL HISTORY (do not regress):
//   (256,4) -> cap 128: sacc spilled to scratch, 580 MB/dispatch HBM (R4).
//   (256,3) -> cap 170: allocator STILL chose 84 VGPR + scratch spill,
//              270 MB/dispatch (R5). The occupancy heuristic sacrifices the
//              accumulator array unless given full headroom.
//   (256,2) -> cap 256: allocator free to keep ~130 live regs resident.
// ---------------------------------------------------------------------------
template<int MODE>
__global__ __launch_bounds__(NTHREADS, 2)
void caps_main(const float* __restrict__ x,
               const float* __restrict__ W,
               const float* __restrict__ bias,
               const float* __restrict__ v_in,
               float* __restrict__ b2,
               float* __restrict__ s_part)
{
    __shared__ float sx[NB][ITOT * EDIM];    // 8 KB
    __shared__ float swv[NWAVES][NB][SCD];   // 20 KB — wave-private slabs

    const int tid = threadIdx.x;
    const int d   = tid & 15;
    const int ch  = (tid >> 4) & 1;
    const int il  = tid >> 5;                // 0..7
    const int wid = tid >> 6;                // 0..3
    const int icb = blockIdx.x;              // 0..35
    const int bcb = blockIdx.y;              // 0..31
    const int i0  = icb * ITOT;
    const int b0  = bcb * NB;

    // ---- stage x slice: 512 float4, 2 per thread, coalesced ----
    {
        const float4* xg = (const float4*)x;
        float4* xs = (float4*)&sx[0][0];
        #pragma unroll
        for (int f = tid; f < NB * ITOT * EDIM / 4; f += NTHREADS) {
            int bb = f >> 6;                 // 64 float4 per b row
            int w  = f & 63;
            xs[f] = xg[(size_t)(b0 + bb) * (IC * EDIM / 4) + i0 * (EDIM / 4) + w];
        }
    }

    float sacc[NB][5];
    #pragma unroll
    for (int bb = 0; bb < NB; ++bb)
        #pragma unroll
        for (int k = 0; k < 5; ++k) sacc[bb][k] = 0.f;

    __syncthreads();

    const float4* Wg = (const float4*)W;

    #pragma unroll 1
    for (int ic = 0; ic < NCHUNK; ++ic) {
        const int i = i0 + ic * ITILE + il;

        // W fragment + bias for this i-chunk
        float4 w4[5][2];
        float  bv[5];
        #pragma unroll
        for (int k = 0; k < 5; ++k) {
            int c = ch * 5 + k;
            size_t base = ((size_t)(i * NC + c) * DV + d) * 2;
            w4[k][0] = Wg[base];
            w4[k][1] = Wg[base + 1];
            bv[k]    = bias[i * NC + c];
        }

        float cw[5];
        if (MODE == 1) {
            // softmax(bias[i,:]) — batch-independent, once per i-chunk
            float mx = fmaxf(fmaxf(fmaxf(bv[0], bv[1]), fmaxf(bv[2], bv[3])), bv[4]);
            mx = fmaxf(mx, __shfl_xor(mx, 16));
            float ssum = 0.f, ex[5];
            #pragma unroll
            for (int k = 0; k < 5; ++k) { ex[k] = __expf(bv[k] - mx); ssum += ex[k]; }
            ssum += __shfl_xor(ssum, 16);
            float inv = 1.0f / ssum;
            #pragma unroll
            for (int k = 0; k < 5; ++k) cw[k] = ex[k] * inv;
        }

        #pragma unroll
        for (int bb = 0; bb < NB; ++bb) {
            const int b = b0 + bb;
            const float4 x0 = ((const float4*)&sx[bb][(ic * ITILE + il) * EDIM])[0];
            const float4 x1 = ((const float4*)&sx[bb][(ic * ITILE + il) * EDIM])[1];

            // u_hat[b, i, c_k, d]
            float u[5];
            #pragma unroll
            for (int k = 0; k < 5; ++k) {
                float acc = w4[k][0].x * x0.x;
                acc = fmaf(w4[k][0].y, x0.y, acc);
                acc = fmaf(w4[k][0].z, x0.z, acc);
                acc = fmaf(w4[k][0].w, x0.w, acc);
                acc = fmaf(w4[k][1].x, x1.x, acc);
                acc = fmaf(w4[k][1].y, x1.y, acc);
                acc = fmaf(w4[k][1].z, x1.z, acc);
                acc = fmaf(w4[k][1].w, x1.w, acc);
                u[k] = acc;
            }

            if (MODE != 1) {
                // agreement: sum over d via DPP; v is small & L2-hot
                const float* vb = v_in + (size_t)b * SCD + ch * 80 + d;
                float t[5];
                #pragma unroll
                for (int k = 0; k < 5; ++k) t[k] = u[k] * vb[k * 16];
                #pragma unroll
                for (int k = 0; k < 5; ++k) t[k] = row_reduce16(t[k]);

                float br[5];
                if (MODE == 2) {
                    #pragma unroll
                    for (int k = 0; k < 5; ++k) br[k] = t[k] + 2.0f * bv[k];
                    if (d == 0) {
                        float* bp = b2 + ((size_t)b * IC + i) * NC + ch * 5;
                        #pragma unroll
                        for (int k = 0; k < 5; ++k) bp[k] = br[k];
                    }
                } else {
                    const float* bp = b2 + ((size_t)b * IC + i) * NC + ch * 5;
                    #pragma unroll
                    for (int k = 0; k < 5; ++k) br[k] = t[k] + bp[k] + bv[k];
                }
                // softmax over 10 c's: 5 local + partner half via xor-16
                float mx = fmaxf(fmaxf(fmaxf(br[0], br[1]), fmaxf(br[2], br[3])), br[4]);
                mx = fmaxf(mx, __shfl_xor(mx, 16));
                float ssum = 0.f, ex[5];
                #pragma unroll
                for (int k = 0; k < 5; ++k) { ex[k] = __expf(br[k] - mx); ssum += ex[k]; }
                ssum += __shfl_xor(ssum, 16);
                float inv = 1.0f / ssum;
                #pragma unroll
                for (int k = 0; k < 5; ++k) cw[k] = ex[k] * inv;
            }

            // register s-accumulation — no LDS, no shuffle, no barrier
            #pragma unroll
            for (int k = 0; k < 5; ++k)
                sacc[bb][k] = fmaf(cw[k], u[k], sacc[bb][k]);
        }
    }

    // ---- epilogue: i-pair reduce + wave slabs + 4-way reduce + flush ----
    #pragma unroll
    for (int bb = 0; bb < NB; ++bb) {
        #pragma unroll
        for (int k = 0; k < 5; ++k) {
            float s = sacc[bb][k] + __shfl_xor(sacc[bb][k], 32);
            if ((tid & 32) == 0)
                swv[wid][bb][ch * 80 + k * 16 + d] = s;
        }
    }
    __syncthreads();
    #pragma unroll
    for (int r = 0; r < (NB * SCD) / NTHREADS; ++r) {   // 5 iterations
        int j  = tid + r * NTHREADS;
        int bb = j / SCD;
        int cd = j - bb * SCD;
        float s = (swv[0][bb][cd] + swv[1][bb][cd])
                + (swv[2][bb][cd] + swv[3][bb][cd]);
        s_part[((size_t)icb * BATCH + b0 + bb) * SCD + cd] = s;
    }
}

// ---------------------------------------------------------------------------
// Reduce s-partials over the 36 slabs and apply squash.
// Block = 16 (b,c) groups x 16 d. Grid = 2560/16 = 160 blocks.
// ---------------------------------------------------------------------------
__global__ __launch_bounds__(256)
void caps_squash(const float* __restrict__ s_part, float* __restrict__ out)
{
    const int tid = threadIdx.x;
    const int bc  = blockIdx.x * 16 + (tid >> 4);
    const size_t off = (size_t)bc * DV + (tid & 15);

    float a[4] = {0.f, 0.f, 0.f, 0.f};
    #pragma unroll
    for (int ic = 0; ic < NSLAB; ic += 4) {
        #pragma unroll
        for (int j = 0; j < 4; ++j)
            a[j] += s_part[(size_t)(ic + j) * SPART_STRIDE + off];
    }
    float s = (a[0] + a[1]) + (a[2] + a[3]);

    float sq = row_reduce16(s * s);

    // scale = sq/(1+sq)/sqrt(sq+EPS), EPS = 1e-7 (matches reference)
    float scale = sq / ((1.0f + sq) * sqrtf(sq + 1e-7f));
    out[off] = scale * s;
}

// ---------------------------------------------------------------------------
extern "C" void kernel_launch(void* const* d_in, const int* in_sizes, int n_in,
                              void* d_out, int out_size, void* d_ws, size_t ws_size,
                              hipStream_t stream)
{
    const float* x    = (const float*)d_in[0];   // [256,1152,8]
    const float* W    = (const float*)d_in[1];   // [1152,10,16,8]
    const float* bias = (const float*)d_in[2];   // [1152,10]
    float* out = (float*)d_out;                  // [256,10,16]

    float* ws     = (float*)d_ws;
    float* s_part = ws;                                       // 36*40960 = 1,474,560 f
    float* v      = s_part + (size_t)NSLAB * SPART_STRIDE;    // 40,960 f
    float* b2     = v + SPART_STRIDE;                         // 2,949,120 f
    // total ws use: ~17.9 MB

    dim3 grid(NSLAB, BCHUNKS);   // 36 x 32 = 1152 blocks

    // iter 1
    caps_main<1><<<grid, NTHREADS, 0, stream>>>(x, W, bias, v, b2, s_part);
    caps_squash<<<160, 256, 0, stream>>>(s_part, v);
    // iter 2
    caps_main<2><<<grid, NTHREADS, 0, stream>>>(x, W, bias, v, b2, s_part);
    caps_squash<<<160, 256, 0, stream>>>(s_part, v);
    // final
    caps_main<3><<<grid, NTHREADS, 0, stream>>>(x, W, bias, v, b2, s_part);
    caps_squash<<<160, 256, 0, stream>>>(s_part, out);
}

// Round 7
// 183.200 us; speedup vs baseline: 2.4453x; 1.0770x over previous
//
#include <hip/hip_runtime.h>
#include <math.h>

// Problem constants
#define BATCH 256
#define IC    1152
#define EDIM  8
#define NC    10
#define DV    16

// Tiling
#define ITILE  8                    // i's covered by thread layout (il = 0..7)
#define NCHUNK 4                    // i-chunks looped per block
#define ITOT   (ITILE * NCHUNK)     // 32 i's per block
#define NB     4                    // b's per block (register s-acc = 20 VGPRs)
#define NTHREADS 256                // 8 il * 2 ch * 16 d
#define NWAVES 4
#define NSLAB  (IC / ITOT)          // 36 partial slabs
#define BCHUNKS (BATCH / NB)        // 64
#define SCD (NC * DV)               // 160
#define SPART_STRIDE (BATCH * SCD)  // 40960 floats per slab

// ---------------------------------------------------------------------------
// DPP-based 16-lane (row) sum reduce — all VALU, no DS pipe. HW-verified.
// ---------------------------------------------------------------------------
template<int CTRL>
__device__ __forceinline__ float dpp_add(float x) {
    int r = __builtin_amdgcn_update_dpp(0, __float_as_int(x), CTRL, 0xF, 0xF, true);
    return x + __int_as_float(r);
}
__device__ __forceinline__ float row_reduce16(float x) {
    x = dpp_add<0xB1>(x);   // quad_perm [1,0,3,2] : xor 1
    x = dpp_add<0x4E>(x);   // quad_perm [2,3,0,1] : xor 2
    x = dpp_add<0x141>(x);  // row_half_mirror     : xor 4
    x = dpp_add<0x140>(x);  // row_mirror          : xor 8
    return x;
}

// ---------------------------------------------------------------------------
// Main fused kernel. tid = il*32 + ch*16 + d.
// Loop: ic (4 i-chunks) outer, bb (4 b's) inner; s-partials in REGISTERS
// sacc[4][5]; one shuffle+LDS reduction in the epilogue.
//
// SPILL HISTORY (do not regress):
//   (256,4) cap 128 : sacc spilled, 580 MB/dispatch scratch HBM (R4).
//   (256,3) cap 170 : allocator chose 84 VGPR + spill, 270 MB (R5).
//   (256,2) cap 256 : allocator chose exactly 128, ~25 MB residual spill (R6,
//                     NB=8 needed ~130 live regs).
//   R7: NB=4 cuts live regs to ~110 < 128 — spill structurally impossible
//       to "prefer" at any boundary the allocator picks.
//
// b2 is PADDED [b][i][ch][8] so each thread-half's 5 logits are 16B-aligned
// contiguous -> dwordx4+dword instead of 5 scalar dwords.
//
// MODE 1: c = softmax(bias)                       -> s1 partials
// MODE 2: b2 = (u.v1) + 2*bias (stored), softmax  -> s2 partials
// MODE 3: b3 = (u.v2) + b2 + bias, softmax        -> s3 partials
// ---------------------------------------------------------------------------
template<int MODE>
__global__ __launch_bounds__(NTHREADS, 2)
void caps_main(const float* __restrict__ x,
               const float* __restrict__ W,
               const float* __restrict__ bias,
               const float* __restrict__ v_in,
               float* __restrict__ b2,
               float* __restrict__ s_part)
{
    __shared__ float sx[NB][ITOT * EDIM];    // 4 KB
    __shared__ float swv[NWAVES][NB][SCD];   // 10 KB — wave-private slabs

    const int tid = threadIdx.x;
    const int d   = tid & 15;
    const int ch  = (tid >> 4) & 1;
    const int il  = tid >> 5;                // 0..7
    const int wid = tid >> 6;                // 0..3
    const int icb = blockIdx.x;              // 0..35
    const int bcb = blockIdx.y;              // 0..63
    const int i0  = icb * ITOT;
    const int b0  = bcb * NB;

    // ---- stage x slice: 256 float4, one per thread, coalesced ----
    {
        const float4* xg = (const float4*)x;
        float4* xs = (float4*)&sx[0][0];
        int bb = tid >> 6;                   // 64 float4 per b row
        int w  = tid & 63;
        xs[tid] = xg[(size_t)(b0 + bb) * (IC * EDIM / 4) + i0 * (EDIM / 4) + w];
    }

    float sacc[NB][5];
    #pragma unroll
    for (int bb = 0; bb < NB; ++bb)
        #pragma unroll
        for (int k = 0; k < 5; ++k) sacc[bb][k] = 0.f;

    __syncthreads();

    const float4* Wg = (const float4*)W;

    #pragma unroll 1
    for (int ic = 0; ic < NCHUNK; ++ic) {
        const int i = i0 + ic * ITILE + il;

        // W fragment + bias for this i-chunk
        float4 w4[5][2];
        float  bv[5];
        #pragma unroll
        for (int k = 0; k < 5; ++k) {
            int c = ch * 5 + k;
            size_t base = ((size_t)(i * NC + c) * DV + d) * 2;
            w4[k][0] = Wg[base];
            w4[k][1] = Wg[base + 1];
            bv[k]    = bias[i * NC + c];
        }

        float cw[5];
        if (MODE == 1) {
            // softmax(bias[i,:]) — batch-independent, once per i-chunk
            float mx = fmaxf(fmaxf(fmaxf(bv[0], bv[1]), fmaxf(bv[2], bv[3])), bv[4]);
            mx = fmaxf(mx, __shfl_xor(mx, 16));
            float ssum = 0.f, ex[5];
            #pragma unroll
            for (int k = 0; k < 5; ++k) { ex[k] = __expf(bv[k] - mx); ssum += ex[k]; }
            ssum += __shfl_xor(ssum, 16);
            float inv = 1.0f / ssum;
            #pragma unroll
            for (int k = 0; k < 5; ++k) cw[k] = ex[k] * inv;
        }

        #pragma unroll
        for (int bb = 0; bb < NB; ++bb) {
            const int b = b0 + bb;
            const float4 x0 = ((const float4*)&sx[bb][(ic * ITILE + il) * EDIM])[0];
            const float4 x1 = ((const float4*)&sx[bb][(ic * ITILE + il) * EDIM])[1];

            // u_hat[b, i, c_k, d]
            float u[5];
            #pragma unroll
            for (int k = 0; k < 5; ++k) {
                float acc = w4[k][0].x * x0.x;
                acc = fmaf(w4[k][0].y, x0.y, acc);
                acc = fmaf(w4[k][0].z, x0.z, acc);
                acc = fmaf(w4[k][0].w, x0.w, acc);
                acc = fmaf(w4[k][1].x, x1.x, acc);
                acc = fmaf(w4[k][1].y, x1.y, acc);
                acc = fmaf(w4[k][1].z, x1.z, acc);
                acc = fmaf(w4[k][1].w, x1.w, acc);
                u[k] = acc;
            }

            if (MODE != 1) {
                // agreement: sum over d via DPP; v is small & L2-hot
                const float* vb = v_in + (size_t)b * SCD + ch * 80 + d;
                float t[5];
                #pragma unroll
                for (int k = 0; k < 5; ++k) t[k] = u[k] * vb[k * 16];
                #pragma unroll
                for (int k = 0; k < 5; ++k) t[k] = row_reduce16(t[k]);

                float br[5];
                float* bp = b2 + (((size_t)b * IC + i) * 2 + ch) * 8;  // padded
                if (MODE == 2) {
                    #pragma unroll
                    for (int k = 0; k < 5; ++k) br[k] = t[k] + 2.0f * bv[k];
                    if (d == 0) {
                        #pragma unroll
                        for (int k = 0; k < 5; ++k) bp[k] = br[k];
                    }
                } else {
                    #pragma unroll
                    for (int k = 0; k < 5; ++k) br[k] = t[k] + bp[k] + bv[k];
                }
                // softmax over 10 c's: 5 local + partner half via xor-16
                float mx = fmaxf(fmaxf(fmaxf(br[0], br[1]), fmaxf(br[2], br[3])), br[4]);
                mx = fmaxf(mx, __shfl_xor(mx, 16));
                float ssum = 0.f, ex[5];
                #pragma unroll
                for (int k = 0; k < 5; ++k) { ex[k] = __expf(br[k] - mx); ssum += ex[k]; }
                ssum += __shfl_xor(ssum, 16);
                float inv = 1.0f / ssum;
                #pragma unroll
                for (int k = 0; k < 5; ++k) cw[k] = ex[k] * inv;
            }

            // register s-accumulation — no LDS, no shuffle, no barrier
            #pragma unroll
            for (int k = 0; k < 5; ++k)
                sacc[bb][k] = fmaf(cw[k], u[k], sacc[bb][k]);
        }
    }

    // ---- epilogue: i-pair reduce + wave slabs + 4-way reduce + flush ----
    #pragma unroll
    for (int bb = 0; bb < NB; ++bb) {
        #pragma unroll
        for (int k = 0; k < 5; ++k) {
            float s = sacc[bb][k] + __shfl_xor(sacc[bb][k], 32);
            if ((tid & 32) == 0)
                swv[wid][bb][ch * 80 + k * 16 + d] = s;
        }
    }
    __syncthreads();
    for (int j = tid; j < NB * SCD; j += NTHREADS) {    // 640 elems
        int bb = j / SCD;
        int cd = j - bb * SCD;
        float s = (swv[0][bb][cd] + swv[1][bb][cd])
                + (swv[2][bb][cd] + swv[3][bb][cd]);
        s_part[((size_t)icb * BATCH + b0 + bb) * SCD + cd] = s;
    }
}

// ---------------------------------------------------------------------------
// Reduce s-partials over the 36 slabs and apply squash.
// Block = 16 (b,c) groups x 16 d. Grid = 2560/16 = 160 blocks.
// ---------------------------------------------------------------------------
__global__ __launch_bounds__(256)
void caps_squash(const float* __restrict__ s_part, float* __restrict__ out)
{
    const int tid = threadIdx.x;
    const int bc  = blockIdx.x * 16 + (tid >> 4);
    const size_t off = (size_t)bc * DV + (tid & 15);

    float a[4] = {0.f, 0.f, 0.f, 0.f};
    #pragma unroll
    for (int ic = 0; ic < NSLAB; ic += 4) {
        #pragma unroll
        for (int j = 0; j < 4; ++j)
            a[j] += s_part[(size_t)(ic + j) * SPART_STRIDE + off];
    }
    float s = (a[0] + a[1]) + (a[2] + a[3]);

    float sq = row_reduce16(s * s);

    // scale = sq/(1+sq)/sqrt(sq+EPS), EPS = 1e-7 (matches reference)
    float scale = sq / ((1.0f + sq) * sqrtf(sq + 1e-7f));
    out[off] = scale * s;
}

// ---------------------------------------------------------------------------
extern "C" void kernel_launch(void* const* d_in, const int* in_sizes, int n_in,
                              void* d_out, int out_size, void* d_ws, size_t ws_size,
                              hipStream_t stream)
{
    const float* x    = (const float*)d_in[0];   // [256,1152,8]
    const float* W    = (const float*)d_in[1];   // [1152,10,16,8]
    const float* bias = (const float*)d_in[2];   // [1152,10]
    float* out = (float*)d_out;                  // [256,10,16]

    float* ws     = (float*)d_ws;
    float* s_part = ws;                                       // 36*40960 = 1,474,560 f
    float* v      = s_part + (size_t)NSLAB * SPART_STRIDE;    // 40,960 f
    float* b2     = v + SPART_STRIDE;                         // padded: 4,718,592 f
    // total ws use: ~25 MB

    dim3 grid(NSLAB, BCHUNKS);   // 36 x 64 = 2304 blocks

    // iter 1
    caps_main<1><<<grid, NTHREADS, 0, stream>>>(x, W, bias, v, b2, s_part);
    caps_squash<<<160, 256, 0, stream>>>(s_part, v);
    // iter 2
    caps_main<2><<<grid, NTHREADS, 0, stream>>>(x, W, bias, v, b2, s_part);
    caps_squash<<<160, 256, 0, stream>>>(s_part, v);
    // final
    caps_main<3><<<grid, NTHREADS, 0, stream>>>(x, W, bias, v, b2, s_part);
    caps_squash<<<160, 256, 0, stream>>>(s_part, out);
}